// Round 6
// baseline (1753.575 us; speedup 1.0000x reference)
//
#include <hip/hip_runtime.h>
#include <math.h>

#define BB 256
#define NN 128
#define DD 512
#define NEGV (-9e15f)

// ---------------------------------------------------------------- K1: star = masked mean over rows
__global__ __launch_bounds__(256) void k_avepool(const float* __restrict__ h,
                                                 const float* __restrict__ mask,
                                                 float* __restrict__ star) {
    const int b = blockIdx.x;
    const int t = threadIdx.x;
    const float* hb = h + (size_t)b * NN * DD;
    const float* mb = mask + (size_t)b * NN;
    float acc0 = 0.f, acc1 = 0.f, L = 0.f;
    for (int n = 0; n < NN; ++n) {
        float m = mb[n];
        L += m;
        acc0 += m * hb[n * DD + t];
        acc1 += m * hb[n * DD + t + 256];
    }
    star[b * DD + t] = acc0 / L;
    star[b * DD + t + 256] = acc1 / L;
}

// ---------------------------------------------------------------- K_step: GAT + gate/noise + attpool, fused.
// one block per batch, 1024 threads (16 waves). All per-element fp chains are
// bit-identical to R1 (score/softmax/PV/mix/attpool bodies preserved).
// jjb-major score jobs -> hj LDS reads broadcast; hS4 double-buffered with
// producer waves staging; PV = R4's 2-rows both-halves (no pS4).
__global__ __launch_bounds__(1024, 1) void k_step(const float* __restrict__ h_in,
                                                  const int* __restrict__ A,
                                                  const float* __restrict__ a0,
                                                  const float* __restrict__ a1,
                                                  const float* __restrict__ a2,
                                                  const float* __restrict__ a3,
                                                  const float* __restrict__ noise_s,
                                                  const float* __restrict__ mask,
                                                  const float* __restrict__ star_in,
                                                  float* __restrict__ star_out,
                                                  float* __restrict__ h_gat,
                                                  float* __restrict__ h_out,
                                                  float* __restrict__ embs,
                                                  int first) {
    __shared__ float4 hA[NN * 17];       // 34.8 KB
    __shared__ float4 hBuf[NN * 17];     // 34.8 KB (double buffer)
    __shared__ float  eselS[NN * 132];   // 67.6 KB
    __shared__ float  starS[DD];
    __shared__ float  simS[NN];
    __shared__ float  wS[NN];
    __shared__ float  sh_M, sh_inv;

    const int tid = threadIdx.x;
    const int b = blockIdx.x;
    const float* __restrict__ hb = h_in + (size_t)b * NN * DD;

    // ---- score job decode, jjb-major: for jjb 0..15, jr 0..4*jjb+3 (544 jobs) ----
    const bool hasJob = tid < 544;
    int jjb = 0, jr = 0;
    if (hasJob) {
        int rem = tid;
        for (int k = 0; k < 16; ++k) {
            int c = 4 * k + 4;
            if (rem < c) { jjb = k; jr = rem; break; }
            rem -= c;
        }
    }
    const int i0 = jr * 2, i1 = i0 + 1;
    const int jb8 = jjb * 8;
    const int swi = (jr >> 2) & 7;
    const int swj = jjb & 7;

    auto stageAll = [&](float4* buf, int d0) {
        #pragma unroll
        for (int q = 0; q < 2; ++q) {
            int l = q * 1024 + tid;
            int row = l >> 4, c4 = l & 15;
            buf[row * 17 + (c4 ^ ((row >> 3) & 7))] = *(const float4*)(hb + row * DD + d0 + c4 * 4);
        }
    };
    auto stageTail = [&](float4* buf, int d0) {   // callers: tid >= 544
        for (int l = tid - 544; l < 2048; l += 480) {
            int row = l >> 4, c4 = l & 15;
            buf[row * 17 + (c4 ^ ((row >> 3) & 7))] = *(const float4*)(hb + row * DD + d0 + c4 * 4);
        }
    };

    float acc0[8][4], acc1[8][4];
    #pragma unroll
    for (int jj = 0; jj < 8; ++jj)
        #pragma unroll
        for (int k = 0; k < 4; ++k) { acc0[jj][k] = 0.f; acc1[jj][k] = 0.f; }

    // ================= score phase (chains exactly R1 per pair; dbuf, producer staging) =================
    stageAll(hA, 0);
    __syncthreads();
    for (int ck = 0; ck < 8; ++ck) {
        const int d0 = ck * 64;
        const float4* cur = (ck & 1) ? hBuf : hA;
        float4* nxt = (ck & 1) ? hA : hBuf;
        if (hasJob) {
            #pragma unroll 2
            for (int c4 = 0; c4 < 16; ++c4) {
                const int dbase = d0 + c4 * 4;
                const float av0x = a0[dbase],     av0y = a1[dbase],     av0z = a2[dbase],     av0w = a3[dbase];
                const float av1x = a0[dbase + 1], av1y = a1[dbase + 1], av1z = a2[dbase + 1], av1w = a3[dbase + 1];
                const float av2x = a0[dbase + 2], av2y = a1[dbase + 2], av2z = a2[dbase + 2], av2w = a3[dbase + 2];
                const float av3x = a0[dbase + 3], av3y = a1[dbase + 3], av3z = a2[dbase + 3], av3w = a3[dbase + 3];
                float4 hi0 = cur[i0 * 17 + (c4 ^ swi)];
                float4 hi1 = cur[i1 * 17 + (c4 ^ swi)];
                #pragma unroll
                for (int jj = 0; jj < 8; ++jj) {
                    float4 hj = cur[(jb8 + jj) * 17 + (c4 ^ swj)];
                    float p;
                    p = hi0.x * hj.x; acc0[jj][0] += p * av0x; acc0[jj][1] += p * av0y; acc0[jj][2] += p * av0z; acc0[jj][3] += p * av0w;
                    p = hi0.y * hj.y; acc0[jj][0] += p * av1x; acc0[jj][1] += p * av1y; acc0[jj][2] += p * av1z; acc0[jj][3] += p * av1w;
                    p = hi0.z * hj.z; acc0[jj][0] += p * av2x; acc0[jj][1] += p * av2y; acc0[jj][2] += p * av2z; acc0[jj][3] += p * av2w;
                    p = hi0.w * hj.w; acc0[jj][0] += p * av3x; acc0[jj][1] += p * av3y; acc0[jj][2] += p * av3z; acc0[jj][3] += p * av3w;
                    p = hi1.x * hj.x; acc1[jj][0] += p * av0x; acc1[jj][1] += p * av0y; acc1[jj][2] += p * av0z; acc1[jj][3] += p * av0w;
                    p = hi1.y * hj.y; acc1[jj][0] += p * av1x; acc1[jj][1] += p * av1y; acc1[jj][2] += p * av1z; acc1[jj][3] += p * av1w;
                    p = hi1.z * hj.z; acc1[jj][0] += p * av2x; acc1[jj][1] += p * av2y; acc1[jj][2] += p * av2z; acc1[jj][3] += p * av2w;
                    p = hi1.w * hj.w; acc1[jj][0] += p * av3x; acc1[jj][1] += p * av3y; acc1[jj][2] += p * av3z; acc1[jj][3] += p * av3w;
                }
            }
        } else if (ck < 7) {
            stageTail(nxt, d0 + 64);
        }
        __syncthreads();
    }

    // ================= selection (both triangles) -> esel; stagers prep PV ck0 =================
    {
        auto selv = [](const float* a4, int Av) -> float {
            float e = (Av == 1) ? a4[0] : (Av == 2) ? a4[1] : (Av == 3) ? a4[2] : a4[3];
            float lr = (e > 0.f) ? e : 0.2f * e;
            return (Av >= 1 && Av <= 4) ? lr : NEGV;
        };
        if (hasJob) {
            const int* __restrict__ Ab = A + (size_t)b * NN * NN;
            #pragma unroll
            for (int jj = 0; jj < 8; ++jj) {
                const int j = jb8 + jj;
                int Av;
                Av = Ab[i0 * NN + j];  eselS[i0 * 132 + j] = selv(acc0[jj], Av);
                Av = Ab[i1 * NN + j];  eselS[i1 * 132 + j] = selv(acc1[jj], Av);
                Av = Ab[j * NN + i0];  eselS[j * 132 + i0] = selv(acc0[jj], Av);
                Av = Ab[j * NN + i1];  eselS[j * 132 + i1] = selv(acc1[jj], Av);
            }
        } else {
            stageTail(hA, 0);   // PV ck0 buffer
        }
        __syncthreads();
    }

    // ================= row softmax — EXACTLY R1's tree and lane mapping =================
    {
        const int it4 = tid >> 8;
        const int sub = tid & 255;
        const int ti = sub >> 4, tj = sub & 15;
        const int li0 = it4 * 32 + ti * 2, li1 = li0 + 1;
        float s0[8], s1[8];
        #pragma unroll
        for (int jj = 0; jj < 8; ++jj) {
            s0[jj] = eselS[li0 * 132 + tj + 16 * jj];
            s1[jj] = eselS[li1 * 132 + tj + 16 * jj];
        }
        float m0 = s0[0], m1 = s1[0];
        #pragma unroll
        for (int jj = 1; jj < 8; ++jj) { m0 = fmaxf(m0, s0[jj]); m1 = fmaxf(m1, s1[jj]); }
        #pragma unroll
        for (int off = 1; off < 16; off <<= 1) {
            m0 = fmaxf(m0, __shfl_xor(m0, off));
            m1 = fmaxf(m1, __shfl_xor(m1, off));
        }
        float e0[8], e1[8], sum0 = 0.f, sum1 = 0.f;
        #pragma unroll
        for (int jj = 0; jj < 8; ++jj) {
            e0[jj] = expf(s0[jj] - m0); sum0 += e0[jj];
            e1[jj] = expf(s1[jj] - m1); sum1 += e1[jj];
        }
        #pragma unroll
        for (int off = 1; off < 16; off <<= 1) {
            sum0 += __shfl_xor(sum0, off);
            sum1 += __shfl_xor(sum1, off);
        }
        #pragma unroll
        for (int jj = 0; jj < 8; ++jj) {
            eselS[li0 * 132 + tj + 16 * jj] = e0[jj] / sum0;
            eselS[li1 * 132 + tj + 16 * jj] = e1[jj] / sum1;
        }
    }
    __syncthreads();

    // ================= PV phase: 2 rows x 1 f4col x both halves (R4 chains), dbuf =================
    const int gd = tid & 15;
    const int gi = tid >> 4;                 // 0..63
    const int pl0 = gi * 2, pl1 = pl0 + 1;
    const float* alp0 = &eselS[pl0 * 132];
    const float* alp1 = &eselS[pl1 * 132];
    for (int ck = 0; ck < 8; ++ck) {
        const int d0 = ck * 64;
        const float4* cur = (ck & 1) ? hBuf : hA;
        float4* nxt = (ck & 1) ? hA : hBuf;
        if (ck < 7) stageAll(nxt, d0 + 64);
        float4 s00 = make_float4(0.f, 0.f, 0.f, 0.f), s10 = s00, s01 = s00, s11 = s00;
        #pragma unroll 4
        for (int jq = 0; jq < 16; ++jq) {
            float4 a0v = *(const float4*)(alp0 + jq * 4);
            float4 a1v = *(const float4*)(alp1 + jq * 4);
            float4 hv;
            hv = cur[(jq * 4 + 0) * 17 + (gd ^ (((jq * 4 + 0) >> 3) & 7))];
            s00.x += a0v.x * hv.x; s00.y += a0v.x * hv.y; s00.z += a0v.x * hv.z; s00.w += a0v.x * hv.w;
            s10.x += a1v.x * hv.x; s10.y += a1v.x * hv.y; s10.z += a1v.x * hv.z; s10.w += a1v.x * hv.w;
            hv = cur[(jq * 4 + 1) * 17 + (gd ^ (((jq * 4 + 1) >> 3) & 7))];
            s00.x += a0v.y * hv.x; s00.y += a0v.y * hv.y; s00.z += a0v.y * hv.z; s00.w += a0v.y * hv.w;
            s10.x += a1v.y * hv.x; s10.y += a1v.y * hv.y; s10.z += a1v.y * hv.z; s10.w += a1v.y * hv.w;
            hv = cur[(jq * 4 + 2) * 17 + (gd ^ (((jq * 4 + 2) >> 3) & 7))];
            s00.x += a0v.z * hv.x; s00.y += a0v.z * hv.y; s00.z += a0v.z * hv.z; s00.w += a0v.z * hv.w;
            s10.x += a1v.z * hv.x; s10.y += a1v.z * hv.y; s10.z += a1v.z * hv.z; s10.w += a1v.z * hv.w;
            hv = cur[(jq * 4 + 3) * 17 + (gd ^ (((jq * 4 + 3) >> 3) & 7))];
            s00.x += a0v.w * hv.x; s00.y += a0v.w * hv.y; s00.z += a0v.w * hv.z; s00.w += a0v.w * hv.w;
            s10.x += a1v.w * hv.x; s10.y += a1v.w * hv.y; s10.z += a1v.w * hv.z; s10.w += a1v.w * hv.w;
        }
        #pragma unroll 4
        for (int jq = 16; jq < 32; ++jq) {
            float4 a0v = *(const float4*)(alp0 + jq * 4);
            float4 a1v = *(const float4*)(alp1 + jq * 4);
            float4 hv;
            hv = cur[(jq * 4 + 0) * 17 + (gd ^ (((jq * 4 + 0) >> 3) & 7))];
            s01.x += a0v.x * hv.x; s01.y += a0v.x * hv.y; s01.z += a0v.x * hv.z; s01.w += a0v.x * hv.w;
            s11.x += a1v.x * hv.x; s11.y += a1v.x * hv.y; s11.z += a1v.x * hv.z; s11.w += a1v.x * hv.w;
            hv = cur[(jq * 4 + 1) * 17 + (gd ^ (((jq * 4 + 1) >> 3) & 7))];
            s01.x += a0v.y * hv.x; s01.y += a0v.y * hv.y; s01.z += a0v.y * hv.z; s01.w += a0v.y * hv.w;
            s11.x += a1v.y * hv.x; s11.y += a1v.y * hv.y; s11.z += a1v.y * hv.z; s11.w += a1v.y * hv.w;
            hv = cur[(jq * 4 + 2) * 17 + (gd ^ (((jq * 4 + 2) >> 3) & 7))];
            s01.x += a0v.z * hv.x; s01.y += a0v.z * hv.y; s01.z += a0v.z * hv.z; s01.w += a0v.z * hv.w;
            s11.x += a1v.z * hv.x; s11.y += a1v.z * hv.y; s11.z += a1v.z * hv.z; s11.w += a1v.z * hv.w;
            hv = cur[(jq * 4 + 3) * 17 + (gd ^ (((jq * 4 + 3) >> 3) & 7))];
            s01.x += a0v.w * hv.x; s01.y += a0v.w * hv.y; s01.z += a0v.w * hv.z; s01.w += a0v.w * hv.w;
            s11.x += a1v.w * hv.x; s11.y += a1v.w * hv.y; s11.z += a1v.w * hv.z; s11.w += a1v.w * hv.w;
        }
        s00.x += s01.x; s00.y += s01.y; s00.z += s01.z; s00.w += s01.w;
        s10.x += s11.x; s10.y += s11.y; s10.z += s11.z; s10.w += s11.w;
        float* outp = h_gat + ((size_t)b * NN + pl0) * DD + d0 + gd * 4;
        *(float4*)(outp)      = s00;
        *(float4*)(outp + DD) = s10;
        __syncthreads();
    }

    __threadfence();
    __syncthreads();

    // ================= mix phase: sigmoid gate + noise + embs (R1 k_mix body, wave = row) =================
    {
        const int wave = tid >> 6, lane = tid & 63;
        const float* stp = star_in + (size_t)b * DD + lane * 8;
        float4 st0 = *(const float4*)(stp);
        float4 st1 = *(const float4*)(stp + 4);
        const float inv3 = 1.0f / 3.0f;
        for (int p = 0; p < 8; ++p) {
            const int row = wave * 8 + p;
            const size_t base = ((size_t)b * NN + row) * DD + lane * 8;
            float4 hg0 = *(const float4*)(h_gat + base);
            float4 hg1 = *(const float4*)(h_gat + base + 4);
            float4 n0 = *(const float4*)(noise_s + base);
            float4 n1 = *(const float4*)(noise_s + base + 4);
            float dot = hg0.x*st0.x + hg0.y*st0.y + hg0.z*st0.z + hg0.w*st0.w
                      + hg1.x*st1.x + hg1.y*st1.y + hg1.z*st1.z + hg1.w*st1.w;
            float nn = n0.x*n0.x + n0.y*n0.y + n0.z*n0.z + n0.w*n0.w
                     + n1.x*n1.x + n1.y*n1.y + n1.z*n1.z + n1.w*n1.w;
            #pragma unroll
            for (int off = 1; off < 64; off <<= 1) {
                dot += __shfl_xor(dot, off);
                nn  += __shfl_xor(nn, off);
            }
            const float sim = dot / 22.62741699796952f;   // / sqrt(512)
            const float al = 1.0f / (1.0f + expf(-sim));
            const float ns = 0.4f / fmaxf(sqrtf(nn), 1e-12f);

            float hm, sg, hn[8];
            float hgv[8] = {hg0.x,hg0.y,hg0.z,hg0.w,hg1.x,hg1.y,hg1.z,hg1.w};
            float stv[8] = {st0.x,st0.y,st0.z,st0.w,st1.x,st1.y,st1.z,st1.w};
            float nv [8] = {n0.x,n0.y,n0.z,n0.w,n1.x,n1.y,n1.z,n1.w};
            #pragma unroll
            for (int c = 0; c < 8; ++c) {
                hm = (1.0f - al) * hgv[c] + al * stv[c];
                sg = (hm > 0.f) ? 1.f : ((hm < 0.f) ? -1.f : 0.f);
                hn[c] = hm + sg * nv[c] * ns;
            }
            float4 w0 = make_float4(hn[0], hn[1], hn[2], hn[3]);
            float4 w1 = make_float4(hn[4], hn[5], hn[6], hn[7]);
            *(float4*)(h_out + base) = w0;
            *(float4*)(h_out + base + 4) = w1;
            if (first) {
                float4 ea = make_float4(hn[0]*inv3, hn[1]*inv3, hn[2]*inv3, hn[3]*inv3);
                float4 eb = make_float4(hn[4]*inv3, hn[5]*inv3, hn[6]*inv3, hn[7]*inv3);
                *(float4*)(embs + base) = ea;
                *(float4*)(embs + base + 4) = eb;
            } else {
                float4 ea = *(const float4*)(embs + base);
                float4 eb = *(const float4*)(embs + base + 4);
                ea.x += hn[0]*inv3; ea.y += hn[1]*inv3; ea.z += hn[2]*inv3; ea.w += hn[3]*inv3;
                eb.x += hn[4]*inv3; eb.y += hn[5]*inv3; eb.z += hn[6]*inv3; eb.w += hn[7]*inv3;
                *(float4*)(embs + base) = ea;
                *(float4*)(embs + base + 4) = eb;
            }
        }
    }

    __threadfence();
    __syncthreads();

    // ================= attpool phase (R1 k_attpool body, wave = row group) =================
    {
        if (tid < 256) {
            starS[tid] = star_in[b * DD + tid];
            starS[tid + 256] = star_in[b * DD + tid + 256];
        }
        __syncthreads();
        const int wave = tid >> 6, lane = tid & 63;
        const float* hb2 = h_out + (size_t)b * NN * DD;
        float4 sv0 = *(const float4*)(&starS[lane * 8]);
        float4 sv1 = *(const float4*)(&starS[lane * 8 + 4]);
        for (int q = 0; q < 8; ++q) {
            const int n = wave * 8 + q;
            const float* hr = hb2 + n * DD + lane * 8;
            float4 h0 = *(const float4*)(hr);
            float4 h1 = *(const float4*)(hr + 4);
            float dot = h0.x*sv0.x + h0.y*sv0.y + h0.z*sv0.z + h0.w*sv0.w
                      + h1.x*sv1.x + h1.y*sv1.y + h1.z*sv1.z + h1.w*sv1.w;
            #pragma unroll
            for (int off = 1; off < 64; off <<= 1) dot += __shfl_xor(dot, off);
            if (lane == 0) simS[n] = dot;
        }
        __syncthreads();
        if (tid < 64) {
            float v = fmaxf(simS[tid], simS[tid + 64]);
            #pragma unroll
            for (int off = 1; off < 64; off <<= 1) v = fmaxf(v, __shfl_xor(v, off));
            if (tid == 0) sh_M = v;
        }
        __syncthreads();
        const float M = sh_M;
        if (tid < NN) wS[tid] = expf(simS[tid] - M) * mask[b * NN + tid];
        __syncthreads();
        if (tid < 64) {
            float v = wS[tid] + wS[tid + 64];
            #pragma unroll
            for (int off = 1; off < 64; off <<= 1) v += __shfl_xor(v, off);
            if (tid == 0) sh_inv = 1.0f / (v + 1e-24f * expf(-M));
        }
        __syncthreads();
        const float inv = sh_inv;
        if (tid < 256) {
            float acc0 = 0.f, acc1 = 0.f;
            for (int n = 0; n < NN; ++n) {
                const float w = wS[n];
                acc0 += w * hb2[n * DD + tid];
                acc1 += w * hb2[n * DD + tid + 256];
            }
            star_out[b * DD + tid] = acc0 * inv;
            star_out[b * DD + tid + 256] = acc1 * inv;
        }
    }
}

// ----------------------------------------------------------------
extern "C" void kernel_launch(void* const* d_in, const int* in_sizes, int n_in,
                              void* d_out, int out_size, void* d_ws, size_t ws_size,
                              hipStream_t stream) {
    const int*   A      = (const int*)d_in[0];
    const float* hidden = (const float*)d_in[1];
    const float* mask   = (const float*)d_in[2];
    const float* a0     = (const float*)d_in[3];
    const float* a1     = (const float*)d_in[4];
    const float* a2     = (const float*)d_in[5];
    const float* a3     = (const float*)d_in[6];
    const float* noise  = (const float*)d_in[7];

    float* out_h    = (float*)d_out;
    float* out_star = out_h + (size_t)BB * NN * DD;
    float* out_embs = out_star + (size_t)BB * DD;

    float* ws_h    = (float*)d_ws;
    float* ws_star = ws_h + (size_t)BB * NN * DD;

    k_avepool<<<BB, 256, 0, stream>>>(hidden, mask, ws_star);

    for (int s = 0; s < 3; ++s) {
        const float* hin = (s == 0) ? hidden : ws_h;
        const float* ns  = noise + (size_t)s * BB * NN * DD;
        float* hout = (s == 2) ? out_h : ws_h;       // step 2: mix in-place on out_h
        float* sout = (s == 2) ? out_star : ws_star;
        k_step<<<BB, 1024, 0, stream>>>(hin, A, a0, a1, a2, a3, ns, mask,
                                        ws_star, sout, out_h, hout, out_embs,
                                        (s == 0) ? 1 : 0);
    }
}

// Round 7
// 969.880 us; speedup vs baseline: 1.8080x; 1.8080x over previous
//
#include <hip/hip_runtime.h>
#include <math.h>

#define BB 256
#define NN 128
#define DD 512
#define NEGV (-9e15f)

// ---------------------------------------------------------------- K1: star = masked mean over rows
__global__ __launch_bounds__(256) void k_avepool(const float* __restrict__ h,
                                                 const float* __restrict__ mask,
                                                 float* __restrict__ star) {
    const int b = blockIdx.x;
    const int t = threadIdx.x;
    const float* hb = h + (size_t)b * NN * DD;
    const float* mb = mask + (size_t)b * NN;
    float acc0 = 0.f, acc1 = 0.f, L = 0.f;
    for (int n = 0; n < NN; ++n) {
        float m = mb[n];
        L += m;
        acc0 += m * hb[n * DD + t];
        acc1 += m * hb[n * DD + t + 256];
    }
    star[b * DD + t] = acc0 / L;
    star[b * DD + t + 256] = acc1 / L;
}

// ---------------------------------------------------------------- K2: GAT — symmetric scores, bit-identical chains to R1
// one block per batch, 1024 threads. jjb-major upper-triangle jobs (hj broadcast),
// all-thread double-buffered staging, PV = 8 rows x 1 f4col x 1 half with
// shfl_xor(16) half-merge (R1's s00+=s01), 512 producers stage next chunk.
__global__ __launch_bounds__(1024, 1) void k_gat(const float* __restrict__ h_in,
                                                 const int* __restrict__ A,
                                                 const float* __restrict__ a0,
                                                 const float* __restrict__ a1,
                                                 const float* __restrict__ a2,
                                                 const float* __restrict__ a3,
                                                 float* __restrict__ h_gat) {
    __shared__ float4 hA[NN * 17];       // 34.8 KB
    __shared__ float4 hB[NN * 17];       // 34.8 KB
    __shared__ float  eselS[NN * 132];   // 67.6 KB

    const int tid = threadIdx.x;
    const int b = blockIdx.x;
    const float* __restrict__ hb = h_in + (size_t)b * NN * DD;

    // ---- score job decode, jjb-major: for jjb 0..15, jr 0..4*jjb+3 (544 jobs) ----
    const bool hasJob = tid < 544;
    int jjb = 0, jr = 0;
    if (hasJob) {
        int rem = tid;
        for (int k = 0; k < 16; ++k) {
            int c = 4 * k + 4;
            if (rem < c) { jjb = k; jr = rem; break; }
            rem -= c;
        }
    }
    const int i0 = jr * 2, i1 = i0 + 1;
    const int jb8 = jjb * 8;
    const int swi = (jr >> 2) & 7;
    const int swj = jjb & 7;

    auto stageAll = [&](float4* buf, int d0) {
        #pragma unroll
        for (int q = 0; q < 2; ++q) {
            int l = q * 1024 + tid;
            int row = l >> 4, c4 = l & 15;
            buf[row * 17 + (c4 ^ ((row >> 3) & 7))] = *(const float4*)(hb + row * DD + d0 + c4 * 4);
        }
    };

    float acc0[8][4], acc1[8][4];
    #pragma unroll
    for (int jj = 0; jj < 8; ++jj)
        #pragma unroll
        for (int k = 0; k < 4; ++k) { acc0[jj][k] = 0.f; acc1[jj][k] = 0.f; }

    // ================= score phase (chains exactly R1 per pair; dbuf all-thread staging) =================
    stageAll(hA, 0);
    __syncthreads();
    for (int ck = 0; ck < 8; ++ck) {
        const int d0 = ck * 64;
        const float4* cur = (ck & 1) ? hB : hA;
        float4* nxt = (ck & 1) ? hA : hB;
        if (ck < 7) stageAll(nxt, d0 + 64);
        if (hasJob) {
            #pragma unroll 2
            for (int c4 = 0; c4 < 16; ++c4) {
                const int dbase = d0 + c4 * 4;
                const float av0x = a0[dbase],     av0y = a1[dbase],     av0z = a2[dbase],     av0w = a3[dbase];
                const float av1x = a0[dbase + 1], av1y = a1[dbase + 1], av1z = a2[dbase + 1], av1w = a3[dbase + 1];
                const float av2x = a0[dbase + 2], av2y = a1[dbase + 2], av2z = a2[dbase + 2], av2w = a3[dbase + 2];
                const float av3x = a0[dbase + 3], av3y = a1[dbase + 3], av3z = a2[dbase + 3], av3w = a3[dbase + 3];
                float4 hi0 = cur[i0 * 17 + (c4 ^ swi)];
                float4 hi1 = cur[i1 * 17 + (c4 ^ swi)];
                #pragma unroll
                for (int jj = 0; jj < 8; ++jj) {
                    float4 hj = cur[(jb8 + jj) * 17 + (c4 ^ swj)];
                    float p;
                    p = hi0.x * hj.x; acc0[jj][0] += p * av0x; acc0[jj][1] += p * av0y; acc0[jj][2] += p * av0z; acc0[jj][3] += p * av0w;
                    p = hi0.y * hj.y; acc0[jj][0] += p * av1x; acc0[jj][1] += p * av1y; acc0[jj][2] += p * av1z; acc0[jj][3] += p * av1w;
                    p = hi0.z * hj.z; acc0[jj][0] += p * av2x; acc0[jj][1] += p * av2y; acc0[jj][2] += p * av2z; acc0[jj][3] += p * av2w;
                    p = hi0.w * hj.w; acc0[jj][0] += p * av3x; acc0[jj][1] += p * av3y; acc0[jj][2] += p * av3z; acc0[jj][3] += p * av3w;
                    p = hi1.x * hj.x; acc1[jj][0] += p * av0x; acc1[jj][1] += p * av0y; acc1[jj][2] += p * av0z; acc1[jj][3] += p * av0w;
                    p = hi1.y * hj.y; acc1[jj][0] += p * av1x; acc1[jj][1] += p * av1y; acc1[jj][2] += p * av1z; acc1[jj][3] += p * av1w;
                    p = hi1.z * hj.z; acc1[jj][0] += p * av2x; acc1[jj][1] += p * av2y; acc1[jj][2] += p * av2z; acc1[jj][3] += p * av2w;
                    p = hi1.w * hj.w; acc1[jj][0] += p * av3x; acc1[jj][1] += p * av3y; acc1[jj][2] += p * av3z; acc1[jj][3] += p * av3w;
                }
            }
        }
        __syncthreads();
    }

    // ================= selection (both triangles) -> esel =================
    {
        auto selv = [](const float* a4, int Av) -> float {
            float e = (Av == 1) ? a4[0] : (Av == 2) ? a4[1] : (Av == 3) ? a4[2] : a4[3];
            float lr = (e > 0.f) ? e : 0.2f * e;
            return (Av >= 1 && Av <= 4) ? lr : NEGV;
        };
        if (hasJob) {
            const int* __restrict__ Ab = A + (size_t)b * NN * NN;
            #pragma unroll
            for (int jj = 0; jj < 8; ++jj) {
                const int j = jb8 + jj;
                int Av;
                Av = Ab[i0 * NN + j];  eselS[i0 * 132 + j] = selv(acc0[jj], Av);
                Av = Ab[i1 * NN + j];  eselS[i1 * 132 + j] = selv(acc1[jj], Av);
                Av = Ab[j * NN + i0];  eselS[j * 132 + i0] = selv(acc0[jj], Av);
                Av = Ab[j * NN + i1];  eselS[j * 132 + i1] = selv(acc1[jj], Av);
            }
        }
        __syncthreads();
    }

    // ================= row softmax — EXACTLY R1's tree and lane mapping =================
    {
        const int it4 = tid >> 8;
        const int sub = tid & 255;
        const int ti = sub >> 4, tj = sub & 15;
        const int li0 = it4 * 32 + ti * 2, li1 = li0 + 1;
        float s0[8], s1[8];
        #pragma unroll
        for (int jj = 0; jj < 8; ++jj) {
            s0[jj] = eselS[li0 * 132 + tj + 16 * jj];
            s1[jj] = eselS[li1 * 132 + tj + 16 * jj];
        }
        float m0 = s0[0], m1 = s1[0];
        #pragma unroll
        for (int jj = 1; jj < 8; ++jj) { m0 = fmaxf(m0, s0[jj]); m1 = fmaxf(m1, s1[jj]); }
        #pragma unroll
        for (int off = 1; off < 16; off <<= 1) {
            m0 = fmaxf(m0, __shfl_xor(m0, off));
            m1 = fmaxf(m1, __shfl_xor(m1, off));
        }
        float e0[8], e1[8], sum0 = 0.f, sum1 = 0.f;
        #pragma unroll
        for (int jj = 0; jj < 8; ++jj) {
            e0[jj] = expf(s0[jj] - m0); sum0 += e0[jj];
            e1[jj] = expf(s1[jj] - m1); sum1 += e1[jj];
        }
        #pragma unroll
        for (int off = 1; off < 16; off <<= 1) {
            sum0 += __shfl_xor(sum0, off);
            sum1 += __shfl_xor(sum1, off);
        }
        #pragma unroll
        for (int jj = 0; jj < 8; ++jj) {
            eselS[li0 * 132 + tj + 16 * jj] = e0[jj] / sum0;
            eselS[li1 * 132 + tj + 16 * jj] = e1[jj] / sum1;
        }
    }
    __syncthreads();

    // ================= PV: 512 consumers (8 rows x 1 f4col x 1 half) + 512 producers =================
    // chain per (i,d): j-half sequential (R1 order), then low += high via shfl_xor(16) (R1 order)
    stageAll(hA, 0);
    __syncthreads();
    const int gd = tid & 15, jh = (tid >> 4) & 1, rg = tid >> 5;   // consumers: tid<512 -> rg 0..15
    const int r0p = rg * 8;
    const int jbase = jh * 64;
#define PVROW(r, ac) { s[r].x += (ac) * hv.x; s[r].y += (ac) * hv.y; s[r].z += (ac) * hv.z; s[r].w += (ac) * hv.w; }
    for (int ck = 0; ck < 8; ++ck) {
        const int d0 = ck * 64;
        const float4* cur = (ck & 1) ? hB : hA;
        float4* nxt = (ck & 1) ? hA : hB;
        if (tid >= 512) {
            if (ck < 7) {
                #pragma unroll
                for (int q = 0; q < 4; ++q) {
                    int l = q * 512 + (tid - 512);
                    int row = l >> 4, c4 = l & 15;
                    nxt[row * 17 + (c4 ^ ((row >> 3) & 7))] = *(const float4*)(hb + row * DD + d0 + 64 + c4 * 4);
                }
            }
        } else {
            float4 s[8];
            #pragma unroll
            for (int r = 0; r < 8; ++r) s[r] = make_float4(0.f, 0.f, 0.f, 0.f);
            #pragma unroll 2
            for (int jq = 0; jq < 16; ++jq) {
                const int j0 = jbase + jq * 4;
                const int swz = (j0 >> 3) & 7;
                float4 av0 = *(const float4*)(&eselS[(r0p + 0) * 132 + j0]);
                float4 av1 = *(const float4*)(&eselS[(r0p + 1) * 132 + j0]);
                float4 av2 = *(const float4*)(&eselS[(r0p + 2) * 132 + j0]);
                float4 av3 = *(const float4*)(&eselS[(r0p + 3) * 132 + j0]);
                float4 av4 = *(const float4*)(&eselS[(r0p + 4) * 132 + j0]);
                float4 av5 = *(const float4*)(&eselS[(r0p + 5) * 132 + j0]);
                float4 av6 = *(const float4*)(&eselS[(r0p + 6) * 132 + j0]);
                float4 av7 = *(const float4*)(&eselS[(r0p + 7) * 132 + j0]);
                float4 hv;
                hv = cur[(j0 + 0) * 17 + (gd ^ swz)];
                PVROW(0, av0.x) PVROW(1, av1.x) PVROW(2, av2.x) PVROW(3, av3.x)
                PVROW(4, av4.x) PVROW(5, av5.x) PVROW(6, av6.x) PVROW(7, av7.x)
                hv = cur[(j0 + 1) * 17 + (gd ^ swz)];
                PVROW(0, av0.y) PVROW(1, av1.y) PVROW(2, av2.y) PVROW(3, av3.y)
                PVROW(4, av4.y) PVROW(5, av5.y) PVROW(6, av6.y) PVROW(7, av7.y)
                hv = cur[(j0 + 2) * 17 + (gd ^ swz)];
                PVROW(0, av0.z) PVROW(1, av1.z) PVROW(2, av2.z) PVROW(3, av3.z)
                PVROW(4, av4.z) PVROW(5, av5.z) PVROW(6, av6.z) PVROW(7, av7.z)
                hv = cur[(j0 + 3) * 17 + (gd ^ swz)];
                PVROW(0, av0.w) PVROW(1, av1.w) PVROW(2, av2.w) PVROW(3, av3.w)
                PVROW(4, av4.w) PVROW(5, av5.w) PVROW(6, av6.w) PVROW(7, av7.w)
            }
            // merge halves: low += high (R1's s00 += s01); jh==1 side discarded
            #pragma unroll
            for (int r = 0; r < 8; ++r) {
                float mx = __shfl_xor(s[r].x, 16);
                float my = __shfl_xor(s[r].y, 16);
                float mz = __shfl_xor(s[r].z, 16);
                float mw = __shfl_xor(s[r].w, 16);
                s[r].x += mx; s[r].y += my; s[r].z += mz; s[r].w += mw;
            }
            if (jh == 0) {
                float* outp = h_gat + ((size_t)b * NN + r0p) * DD + d0 + gd * 4;
                #pragma unroll
                for (int r = 0; r < 8; ++r) *(float4*)(outp + (size_t)r * DD) = s[r];
            }
        }
        __syncthreads();
    }
#undef PVROW
}

// ---------------------------------------------------------------- K2b: sigmoid gate toward star + noise + embs acc
__global__ __launch_bounds__(256) void k_mix(const float* __restrict__ h_gat,
                                             const float* __restrict__ star,
                                             const float* __restrict__ noise_s,
                                             float* __restrict__ h_out,
                                             float* __restrict__ embs,
                                             int first) {
    const int b = blockIdx.y;
    const int tid = threadIdx.x;
    const int wave = tid >> 6, lane = tid & 63;
    const int row0 = blockIdx.x * 16 + wave * 4;
    const float* stp = star + (size_t)b * DD + lane * 8;
    float4 st0 = *(const float4*)(stp);
    float4 st1 = *(const float4*)(stp + 4);
    const float inv3 = 1.0f / 3.0f;

    for (int rr = 0; rr < 4; ++rr) {
        const int row = row0 + rr;
        const size_t base = ((size_t)b * NN + row) * DD + lane * 8;
        float4 hg0 = *(const float4*)(h_gat + base);
        float4 hg1 = *(const float4*)(h_gat + base + 4);
        float4 n0 = *(const float4*)(noise_s + base);
        float4 n1 = *(const float4*)(noise_s + base + 4);
        float dot = hg0.x*st0.x + hg0.y*st0.y + hg0.z*st0.z + hg0.w*st0.w
                  + hg1.x*st1.x + hg1.y*st1.y + hg1.z*st1.z + hg1.w*st1.w;
        float nn = n0.x*n0.x + n0.y*n0.y + n0.z*n0.z + n0.w*n0.w
                 + n1.x*n1.x + n1.y*n1.y + n1.z*n1.z + n1.w*n1.w;
        #pragma unroll
        for (int off = 1; off < 64; off <<= 1) {
            dot += __shfl_xor(dot, off);
            nn  += __shfl_xor(nn, off);
        }
        const float sim = dot / 22.62741699796952f;   // / sqrt(512)
        const float al = 1.0f / (1.0f + expf(-sim));
        const float ns = 0.4f / fmaxf(sqrtf(nn), 1e-12f);

        float hm, sg, hn[8];
        float hgv[8] = {hg0.x,hg0.y,hg0.z,hg0.w,hg1.x,hg1.y,hg1.z,hg1.w};
        float stv[8] = {st0.x,st0.y,st0.z,st0.w,st1.x,st1.y,st1.z,st1.w};
        float nv [8] = {n0.x,n0.y,n0.z,n0.w,n1.x,n1.y,n1.z,n1.w};
        #pragma unroll
        for (int c = 0; c < 8; ++c) {
            hm = (1.0f - al) * hgv[c] + al * stv[c];
            sg = (hm > 0.f) ? 1.f : ((hm < 0.f) ? -1.f : 0.f);
            hn[c] = hm + sg * nv[c] * ns;
        }
        float4 w0 = make_float4(hn[0], hn[1], hn[2], hn[3]);
        float4 w1 = make_float4(hn[4], hn[5], hn[6], hn[7]);
        *(float4*)(h_out + base) = w0;
        *(float4*)(h_out + base + 4) = w1;
        if (first) {
            float4 ea = make_float4(hn[0]*inv3, hn[1]*inv3, hn[2]*inv3, hn[3]*inv3);
            float4 eb = make_float4(hn[4]*inv3, hn[5]*inv3, hn[6]*inv3, hn[7]*inv3);
            *(float4*)(embs + base) = ea;
            *(float4*)(embs + base + 4) = eb;
        } else {
            float4 ea = *(const float4*)(embs + base);
            float4 eb = *(const float4*)(embs + base + 4);
            ea.x += hn[0]*inv3; ea.y += hn[1]*inv3; ea.z += hn[2]*inv3; ea.w += hn[3]*inv3;
            eb.x += hn[4]*inv3; eb.y += hn[5]*inv3; eb.z += hn[6]*inv3; eb.w += hn[7]*inv3;
            *(float4*)(embs + base) = ea;
            *(float4*)(embs + base + 4) = eb;
        }
    }
}

// ---------------------------------------------------------------- K3: attention pooling star update
__global__ __launch_bounds__(256) void k_attpool(const float* __restrict__ h,
                                                 const float* __restrict__ star_in,
                                                 const float* __restrict__ mask,
                                                 float* __restrict__ star_out) {
    __shared__ float starS[DD];
    __shared__ float simS[NN];
    __shared__ float wS[NN];
    __shared__ float sh_M, sh_inv;
    const int b = blockIdx.x;
    const int tid = threadIdx.x;
    starS[tid] = star_in[b * DD + tid];
    starS[tid + 256] = star_in[b * DD + tid + 256];
    __syncthreads();
    const int wave = tid >> 6, lane = tid & 63;
    const float* hb = h + (size_t)b * NN * DD;
    float4 sv0 = *(const float4*)(&starS[lane * 8]);
    float4 sv1 = *(const float4*)(&starS[lane * 8 + 4]);
    for (int q = 0; q < 32; ++q) {
        const int n = wave * 32 + q;
        const float* hr = hb + n * DD + lane * 8;
        float4 h0 = *(const float4*)(hr);
        float4 h1 = *(const float4*)(hr + 4);
        float dot = h0.x*sv0.x + h0.y*sv0.y + h0.z*sv0.z + h0.w*sv0.w
                  + h1.x*sv1.x + h1.y*sv1.y + h1.z*sv1.z + h1.w*sv1.w;
        #pragma unroll
        for (int off = 1; off < 64; off <<= 1) dot += __shfl_xor(dot, off);
        if (lane == 0) simS[n] = dot;
    }
    __syncthreads();
    if (tid < 64) {
        float v = fmaxf(simS[tid], simS[tid + 64]);
        #pragma unroll
        for (int off = 1; off < 64; off <<= 1) v = fmaxf(v, __shfl_xor(v, off));
        if (tid == 0) sh_M = v;
    }
    __syncthreads();
    const float M = sh_M;
    if (tid < NN) wS[tid] = expf(simS[tid] - M) * mask[b * NN + tid];
    __syncthreads();
    if (tid < 64) {
        float v = wS[tid] + wS[tid + 64];
        #pragma unroll
        for (int off = 1; off < 64; off <<= 1) v += __shfl_xor(v, off);
        if (tid == 0) sh_inv = 1.0f / (v + 1e-24f * expf(-M));
    }
    __syncthreads();
    const float inv = sh_inv;
    float acc0 = 0.f, acc1 = 0.f;
    for (int n = 0; n < NN; ++n) {
        const float w = wS[n];
        acc0 += w * hb[n * DD + tid];
        acc1 += w * hb[n * DD + tid + 256];
    }
    star_out[b * DD + tid] = acc0 * inv;
    star_out[b * DD + tid + 256] = acc1 * inv;
}

// ----------------------------------------------------------------
extern "C" void kernel_launch(void* const* d_in, const int* in_sizes, int n_in,
                              void* d_out, int out_size, void* d_ws, size_t ws_size,
                              hipStream_t stream) {
    const int*   A      = (const int*)d_in[0];
    const float* hidden = (const float*)d_in[1];
    const float* mask   = (const float*)d_in[2];
    const float* a0     = (const float*)d_in[3];
    const float* a1     = (const float*)d_in[4];
    const float* a2     = (const float*)d_in[5];
    const float* a3     = (const float*)d_in[6];
    const float* noise  = (const float*)d_in[7];

    float* out_h    = (float*)d_out;
    float* out_star = out_h + (size_t)BB * NN * DD;
    float* out_embs = out_star + (size_t)BB * DD;

    float* ws_h    = (float*)d_ws;
    float* ws_star = ws_h + (size_t)BB * NN * DD;

    k_avepool<<<BB, 256, 0, stream>>>(hidden, mask, ws_star);

    for (int s = 0; s < 3; ++s) {
        const float* hin = (s == 0) ? hidden : ws_h;
        k_gat<<<BB, 1024, 0, stream>>>(hin, A, a0, a1, a2, a3, out_h);
        const float* ns = noise + (size_t)s * BB * NN * DD;
        float* hout = (s == 2) ? out_h : ws_h;
        k_mix<<<dim3(8, BB), 256, 0, stream>>>(out_h, ws_star, ns, hout, out_embs, (s == 0) ? 1 : 0);
        float* so = (s == 2) ? out_star : ws_star;
        k_attpool<<<BB, 256, 0, stream>>>(hout, ws_star, mask, so);
    }
}